// Round 7
// baseline (2385.597 us; speedup 1.0000x reference)
//
#include <hip/hip_runtime.h>

// WRGCN: out[t] = sum_r (sum_{e:tgt=t,rel=r} ew_e * X[src_e]) @ W_r + X[t] @ W_self + P @ bias
// Counting-sort edges by key = r*N + tgt. k_main: 512 thr / 64 targets. Per relation, the
// block's edges are ONE contiguous sorted range; all 8 waves process it edge-parallel
// (8-edge batches, strided column-slice gathers) accumulating into a f32 LDS tile via
// ds_add_f32, then MFMA with f32->bf16 pack-in-fragment. Self term streams from global X.

#define N_ENT 200000
#define D 256
#define R_REL 8
#define E_EDGE 150000
#define TOT_E (R_REL * E_EDGE)        // 1,200,000
#define MKEY (N_ENT * R_REL)          // 1,600,000
#define SCAN_B 1024
#define NBLK_SCAN ((MKEY + SCAN_B - 1) / SCAN_B)   // 1563

typedef __bf16 bf16x8 __attribute__((ext_vector_type(8)));
typedef unsigned short u16x8 __attribute__((ext_vector_type(8)));
typedef float f32x4 __attribute__((ext_vector_type(4)));

__device__ __forceinline__ unsigned short f2bf(float f) {
  unsigned int u = __builtin_bit_cast(unsigned int, f);
  u += 0x7FFFu + ((u >> 16) & 1u);   // RNE (inputs finite)
  return (unsigned short)(u >> 16);
}
__device__ __forceinline__ float bf2f(unsigned short u) {
  return __builtin_bit_cast(float, ((unsigned)u) << 16);
}
__device__ __forceinline__ f32x4 mfma16(u16x8 a, u16x8 b, f32x4 c) {
  return __builtin_amdgcn_mfma_f32_16x16x32_bf16(
      __builtin_bit_cast(bf16x8, a), __builtin_bit_cast(bf16x8, b), c, 0, 0, 0);
}
__device__ __forceinline__ u16x8 pack8(f32x4 lo, f32x4 hi) {
  bf16x8 h;
  h[0] = (__bf16)lo[0]; h[1] = (__bf16)lo[1]; h[2] = (__bf16)lo[2]; h[3] = (__bf16)lo[3];
  h[4] = (__bf16)hi[0]; h[5] = (__bf16)hi[1]; h[6] = (__bf16)hi[2]; h[7] = (__bf16)hi[3];
  return __builtin_bit_cast(u16x8, h);
}

// ---- X (f32) -> Xh (bf16) ----
__global__ __launch_bounds__(256) void k_cvt_x(const float* __restrict__ x,
                                               unsigned short* __restrict__ xh) {
  int i = blockIdx.x * 256 + threadIdx.x;
  const float4* xv = (const float4*)x;
  float4 a = xv[2 * i], b = xv[2 * i + 1];
  uint4 o;
  o.x = (unsigned)f2bf(a.x) | ((unsigned)f2bf(a.y) << 16);
  o.y = (unsigned)f2bf(a.z) | ((unsigned)f2bf(a.w) << 16);
  o.z = (unsigned)f2bf(b.x) | ((unsigned)f2bf(b.y) << 16);
  o.w = (unsigned)f2bf(b.z) | ((unsigned)f2bf(b.w) << 16);
  ((uint4*)xh)[i] = o;
}

// ---- Weights -> bf16 MFMA B-fragment order. tile 0..7 = W_r, 8 = self ----
__global__ __launch_bounds__(256) void k_cvt_w(const float* __restrict__ relw,
                                               const float* __restrict__ selfw,
                                               unsigned short* __restrict__ wf) {
  int t = blockIdx.x * 256 + threadIdx.x;   // 9*8*16*64 = 73728
  int rel = t >> 13;
  int rem = t & 8191;
  int kb = rem >> 10;
  int nb = (rem >> 6) & 15;
  int lane = rem & 63;
  const float* W = (rel < R_REL) ? (relw + rel * D * D) : selfw;
  int k0 = kb * 32 + (lane >> 4) * 8;
  int n = nb * 16 + (lane & 15);
  unsigned int o[4];
#pragma unroll
  for (int jj = 0; jj < 4; ++jj) {
    unsigned lo = f2bf(W[(k0 + 2 * jj) * D + n]);
    unsigned hi = f2bf(W[(k0 + 2 * jj + 1) * D + n]);
    o[jj] = lo | (hi << 16);
  }
  ((uint4*)wf)[t] = make_uint4(o[0], o[1], o[2], o[3]);
}

// ---- bias -> B-fragment tile for K=8 presence MFMA ----
__global__ __launch_bounds__(256) void k_cvt_bias(const float* __restrict__ bias,
                                                  unsigned short* __restrict__ bb) {
  int t = blockIdx.x * 256 + threadIdx.x;   // 1024
  int nb = t >> 6, lane = t & 63;
  int lk = lane >> 4, n = nb * 16 + (lane & 15);
  unsigned int o[4];
#pragma unroll
  for (int jj = 0; jj < 4; ++jj) {
    unsigned lo = 0, hi = 0;
    if (lk == 0) {
      lo = f2bf(bias[(2 * jj) * D + n]);
      hi = f2bf(bias[(2 * jj + 1) * D + n]);
    }
    o[jj] = lo | (hi << 16);
  }
  ((uint4*)bb)[t] = make_uint4(o[0], o[1], o[2], o[3]);
}

// ---- histogram over key = r*N + tgt ----
__global__ __launch_bounds__(256) void k_hist(const int* __restrict__ ei,
                                              unsigned* __restrict__ counts) {
  int t = blockIdx.x * 256 + threadIdx.x;
  if (t >= TOT_E) return;
  int r = t / E_EDGE, e = t - r * E_EDGE;
  int tgt = ei[(r * 2 + 1) * E_EDGE + e];
  atomicAdd(&counts[r * N_ENT + tgt], 1u);
}

// ---- exclusive scan (3 kernels) ----
__global__ __launch_bounds__(256) void k_scan1(const unsigned* __restrict__ cnt,
                                               unsigned* __restrict__ off,
                                               unsigned* __restrict__ aux) {
  __shared__ unsigned sc[256];
  int tid = threadIdx.x;
  int base = blockIdx.x * SCAN_B + tid * 4;
  unsigned v[4];
#pragma unroll
  for (int j = 0; j < 4; ++j) v[j] = (base + j < MKEY) ? cnt[base + j] : 0u;
  unsigned s = v[0] + v[1] + v[2] + v[3];
  sc[tid] = s;
  __syncthreads();
  for (int o = 1; o < 256; o <<= 1) {
    unsigned t = (tid >= o) ? sc[tid - o] : 0u;
    __syncthreads();
    sc[tid] += t;
    __syncthreads();
  }
  unsigned excl = sc[tid] - s;
  if (tid == 255) aux[blockIdx.x] = sc[255];
#pragma unroll
  for (int j = 0; j < 4; ++j) {
    if (base + j < MKEY) off[base + j] = excl;
    excl += v[j];
  }
}

__global__ __launch_bounds__(256) void k_scan2(unsigned* __restrict__ aux) {
  __shared__ unsigned sc[256];
  int tid = threadIdx.x;
  int base = tid * 7;
  unsigned v[7];
#pragma unroll
  for (int j = 0; j < 7; ++j) v[j] = (base + j < NBLK_SCAN) ? aux[base + j] : 0u;
  unsigned s = 0;
#pragma unroll
  for (int j = 0; j < 7; ++j) s += v[j];
  sc[tid] = s;
  __syncthreads();
  for (int o = 1; o < 256; o <<= 1) {
    unsigned t = (tid >= o) ? sc[tid - o] : 0u;
    __syncthreads();
    sc[tid] += t;
    __syncthreads();
  }
  unsigned excl = sc[tid] - s;
#pragma unroll
  for (int j = 0; j < 7; ++j) {
    if (base + j < NBLK_SCAN) aux[base + j] = excl;
    excl += v[j];
  }
}

__global__ __launch_bounds__(256) void k_scan3(unsigned* __restrict__ off,
                                               const unsigned* __restrict__ aux) {
  unsigned add = aux[blockIdx.x];
  int base = blockIdx.x * SCAN_B + threadIdx.x * 4;
  if (base + 3 < MKEY) {
    uint4* p = (uint4*)(off + base);
    uint4 x = *p;
    x.x += add; x.y += add; x.z += add; x.w += add;
    *p = x;
  } else {
    for (int j = 0; j < 4; ++j)
      if (base + j < MKEY) off[base + j] += add;
  }
}

// ---- scatter (src | (tgt&63)<<18, ew); off becomes segment ENDs ----
__global__ __launch_bounds__(256) void k_scatter(const int* __restrict__ ei,
                                                 const float* __restrict__ ew,
                                                 unsigned* __restrict__ off,
                                                 unsigned* __restrict__ spack,
                                                 float* __restrict__ sewt) {
  int t = blockIdx.x * 256 + threadIdx.x;
  if (t >= TOT_E) return;
  int r = t / E_EDGE, e = t - r * E_EDGE;
  int tgt = ei[(r * 2 + 1) * E_EDGE + e];
  int src = ei[(r * 2) * E_EDGE + e];
  float w = ew[t];
  unsigned pos = atomicAdd(&off[r * N_ENT + tgt], 1u);
  spack[pos] = (unsigned)src | ((unsigned)(tgt & 63) << 18);
  sewt[pos] = w;
}

// ---- fused main: 512 threads, 64 targets/block ----
__global__ __launch_bounds__(512, 2) void k_main(const unsigned short* __restrict__ xh,
                                                 const unsigned short* __restrict__ wf,
                                                 const unsigned short* __restrict__ bbf,
                                                 const unsigned* __restrict__ counts,
                                                 const unsigned* __restrict__ off_end,
                                                 const unsigned* __restrict__ spack,
                                                 const float* __restrict__ sewt,
                                                 float* __restrict__ out) {
  __shared__ __align__(16) unsigned char Ls[65536];   // 64x256 f32 tile, XOR-swizzled
  int n0 = blockIdx.x * 64;
  int tid = threadIdx.x;
  int w = tid >> 6, lane = tid & 63;
  int lm = lane & 15, lk = lane >> 4;
  int rbase = (w >> 2) * 32;          // wave's 32-row half for MFMA
  int cbase = (w & 3) * 4;            // wave's 4 nb columns (64 cols)

  f32x4 acc[2][4] = {};

  // ---- self phase: A-frags direct from global bf16 X ----
  {
    const unsigned short* wfb = wf + 8 * 65536;
#pragma unroll
    for (int kb = 0; kb < 8; ++kb) {
      u16x8 a[2], b[4];
#pragma unroll
      for (int mi = 0; mi < 2; ++mi)
        a[mi] = *(const u16x8*)(xh + (size_t)(n0 + rbase + mi * 16 + lm) * 256 + kb * 32 + lk * 8);
#pragma unroll
      for (int ni = 0; ni < 4; ++ni)
        b[ni] = *(const u16x8*)(wfb + ((kb * 16 + cbase + ni) * 64 + lane) * 8);
#pragma unroll
      for (int mi = 0; mi < 2; ++mi)
#pragma unroll
        for (int ni = 0; ni < 4; ++ni)
          acc[mi][ni] = mfma16(a[mi], b[ni], acc[mi][ni]);
    }
  }

  for (int r = 0; r < 8; ++r) {
    // contiguous edge range for this (block, relation): keys k0..k0+63
    int k0 = r * N_ENT + n0;
    unsigned e0 = off_end[k0 + 63];
    unsigned s0 = off_end[k0] - counts[k0];
    if (e0 == s0) continue;   // block-uniform: no edges for this relation

    // zero f32 tile (throughput-bound b128 stores, ~8 per thread)
    f32x4 z4 = {0.f, 0.f, 0.f, 0.f};
#pragma unroll
    for (int z = 0; z < 8; ++z)
      *(f32x4*)(Ls + z * 8192 + tid * 16) = z4;
    __syncthreads();

    // edge-parallel: wave w takes consecutive chunks [s0+w*8+64b, +8)
    for (unsigned base = s0 + (unsigned)w * 8u; base < e0; base += 64u) {
      unsigned pk[8];
      float wt[8];
#pragma unroll
      for (int u = 0; u < 8; ++u) {
        unsigned ii = base + (unsigned)u;
        bool v = ii < e0;
        pk[u] = v ? spack[ii] : 0u;
        wt[u] = v ? sewt[ii] : 0.0f;
      }
      unsigned short xs[8][4];
#pragma unroll
      for (int u = 0; u < 8; ++u) {
        const unsigned short* xr = xh + (size_t)(pk[u] & 0x3FFFFu) * 256 + lane;
        xs[u][0] = xr[0];
        xs[u][1] = xr[64];
        xs[u][2] = xr[128];
        xs[u][3] = xr[192];
      }
#pragma unroll
      for (int u = 0; u < 8; ++u) {
        unsigned g = pk[u] >> 18;
        unsigned bb = g * 1024u, sw = (g & 7u) << 4;
        float wv = wt[u];
        atomicAdd((float*)(Ls + ((bb + lane * 4) ^ sw)), wv * bf2f(xs[u][0]));
        atomicAdd((float*)(Ls + ((bb + 256 + lane * 4) ^ sw)), wv * bf2f(xs[u][1]));
        atomicAdd((float*)(Ls + ((bb + 512 + lane * 4) ^ sw)), wv * bf2f(xs[u][2]));
        atomicAdd((float*)(Ls + ((bb + 768 + lane * 4) ^ sw)), wv * bf2f(xs[u][3]));
      }
    }
    __syncthreads();

    // MFMA: A-frags = 2 x b128 f32 reads + pack to bf16
    const unsigned short* wfb = wf + r * 65536;
#pragma unroll
    for (int kb = 0; kb < 8; ++kb) {
      u16x8 a[2], b[4];
#pragma unroll
      for (int mi = 0; mi < 2; ++mi) {
        int row = rbase + mi * 16 + lm;
        unsigned c4 = (unsigned)(kb * 128 + lk * 32);
        unsigned sw = (unsigned)((row & 7) << 4);
        f32x4 lo = *(const f32x4*)(Ls + ((row * 1024 + c4) ^ sw));
        f32x4 hi = *(const f32x4*)(Ls + ((row * 1024 + c4 + 16) ^ sw));
        a[mi] = pack8(lo, hi);
      }
#pragma unroll
      for (int ni = 0; ni < 4; ++ni)
        b[ni] = *(const u16x8*)(wfb + ((kb * 16 + cbase + ni) * 64 + lane) * 8);
#pragma unroll
      for (int mi = 0; mi < 2; ++mi)
#pragma unroll
        for (int ni = 0; ni < 4; ++ni)
          acc[mi][ni] = mfma16(a[mi], b[ni], acc[mi][ni]);
    }
    __syncthreads();
  }

  // ---- bias via presence MFMA: P[64x8] @ bias[8x256] ----
  {
    u16x8 bb[4];
#pragma unroll
    for (int ni = 0; ni < 4; ++ni)
      bb[ni] = *(const u16x8*)(bbf + ((cbase + ni) * 64 + lane) * 8);
#pragma unroll
    for (int mi = 0; mi < 2; ++mi) {
      u16x8 pa = {};
      if (lk == 0) {
        int n = n0 + rbase + mi * 16 + lm;
#pragma unroll
        for (int r = 0; r < 8; ++r)
          pa[r] = counts[r * N_ENT + n] ? 0x3F80 : 0;
      }
#pragma unroll
      for (int ni = 0; ni < 4; ++ni)
        acc[mi][ni] = mfma16(pa, bb[ni], acc[mi][ni]);
    }
  }

  // ---- epilogue ----
#pragma unroll
  for (int mi = 0; mi < 2; ++mi)
#pragma unroll
    for (int ni = 0; ni < 4; ++ni) {
      int col = (w & 3) * 64 + ni * 16 + lm;
#pragma unroll
      for (int j = 0; j < 4; ++j) {
        int row = n0 + rbase + mi * 16 + lk * 4 + j;
        out[row * 256 + col] = acc[mi][ni][j];
      }
    }
}

extern "C" void kernel_launch(void* const* d_in, const int* in_sizes, int n_in,
                              void* d_out, int out_size, void* d_ws, size_t ws_size,
                              hipStream_t stream) {
  const float* x = (const float*)d_in[0];
  const float* relw = (const float*)d_in[1];
  const float* selfw = (const float*)d_in[2];
  const float* bias = (const float*)d_in[3];
  const int* ei = (const int*)d_in[4];
  const float* ew = (const float*)d_in[5];
  float* out = (float*)d_out;

  char* ws = (char*)d_ws;
  unsigned short* xh = (unsigned short*)ws;                          // 102,400,000
  unsigned short* wf = (unsigned short*)(ws + 102400000);            //   1,179,648
  unsigned short* bbf = (unsigned short*)(ws + 103579648);           //      16,384
  unsigned* counts = (unsigned*)(ws + 103596032);                    //   6,400,000
  unsigned* offs = (unsigned*)(ws + 109996032);                      //   6,400,000
  unsigned* aux = (unsigned*)(ws + 116396032);                       //       8,192
  unsigned* spack = (unsigned*)(ws + 116404224);                     //   4,800,000
  float* sewt = (float*)(ws + 121204224);                            //   4,800,000

  hipMemsetAsync(counts, 0, (size_t)MKEY * 4, stream);
  k_cvt_x<<<(N_ENT * D) / 2048, 256, 0, stream>>>(x, xh);
  k_cvt_w<<<288, 256, 0, stream>>>(relw, selfw, wf);
  k_cvt_bias<<<4, 256, 0, stream>>>(bias, bbf);
  k_hist<<<(TOT_E + 255) / 256, 256, 0, stream>>>(ei, counts);
  k_scan1<<<NBLK_SCAN, 256, 0, stream>>>(counts, offs, aux);
  k_scan2<<<1, 256, 0, stream>>>(aux);
  k_scan3<<<NBLK_SCAN, 256, 0, stream>>>(offs, aux);
  k_scatter<<<(TOT_E + 255) / 256, 256, 0, stream>>>(ei, ew, offs, spack, sewt);
  k_main<<<N_ENT / 64, 512, 0, stream>>>(xh, wf, bbf, counts, offs, spack, sewt, out);
}

// Round 8
// 1611.302 us; speedup vs baseline: 1.4805x; 1.4805x over previous
//
#include <hip/hip_runtime.h>

// WRGCN: out[t] = sum_r (sum_{e:tgt=t,rel=r} ew_e * X[src_e]) @ W_r + X[t] @ W_self + P @ bias
// Counting-sort edges by key = r*N + tgt. k_main is BARRIER-FREE: each wave owns a 32-target
// tile; per relation the wave's edges are one contiguous sorted range; shfl-broadcast meta,
// 8-deep independent gathers, run-length f32 register accumulation (sorted keys) flushed as
// bf16 into a wave-private swizzled LDS tile, then 16x16x32 MFMA over all 16 n-blocks.

#define N_ENT 200000
#define D 256
#define R_REL 8
#define E_EDGE 150000
#define TOT_E (R_REL * E_EDGE)        // 1,200,000
#define MKEY (N_ENT * R_REL)          // 1,600,000
#define SCAN_B 1024
#define NBLK_SCAN ((MKEY + SCAN_B - 1) / SCAN_B)   // 1563
#define NTILE 6250                    // N_ENT / 32

typedef __bf16 bf16x8 __attribute__((ext_vector_type(8)));
typedef unsigned short u16x8 __attribute__((ext_vector_type(8)));
typedef float f32x4 __attribute__((ext_vector_type(4)));

__device__ __forceinline__ unsigned short f2bf(float f) {
  unsigned int u = __builtin_bit_cast(unsigned int, f);
  u += 0x7FFFu + ((u >> 16) & 1u);   // RNE (inputs finite)
  return (unsigned short)(u >> 16);
}
__device__ __forceinline__ float bf2f(unsigned short u) {
  return __builtin_bit_cast(float, ((unsigned)u) << 16);
}
__device__ __forceinline__ f32x4 mfma16(u16x8 a, u16x8 b, f32x4 c) {
  return __builtin_amdgcn_mfma_f32_16x16x32_bf16(
      __builtin_bit_cast(bf16x8, a), __builtin_bit_cast(bf16x8, b), c, 0, 0, 0);
}

// ---- X (f32) -> Xh (bf16) ----
__global__ __launch_bounds__(256) void k_cvt_x(const float* __restrict__ x,
                                               unsigned short* __restrict__ xh) {
  int i = blockIdx.x * 256 + threadIdx.x;
  const float4* xv = (const float4*)x;
  float4 a = xv[2 * i], b = xv[2 * i + 1];
  uint4 o;
  o.x = (unsigned)f2bf(a.x) | ((unsigned)f2bf(a.y) << 16);
  o.y = (unsigned)f2bf(a.z) | ((unsigned)f2bf(a.w) << 16);
  o.z = (unsigned)f2bf(b.x) | ((unsigned)f2bf(b.y) << 16);
  o.w = (unsigned)f2bf(b.z) | ((unsigned)f2bf(b.w) << 16);
  ((uint4*)xh)[i] = o;
}

// ---- Weights -> bf16 MFMA B-fragment order. tile 0..7 = W_r, 8 = self ----
__global__ __launch_bounds__(256) void k_cvt_w(const float* __restrict__ relw,
                                               const float* __restrict__ selfw,
                                               unsigned short* __restrict__ wf) {
  int t = blockIdx.x * 256 + threadIdx.x;   // 9*8*16*64 = 73728
  int rel = t >> 13;
  int rem = t & 8191;
  int kb = rem >> 10;
  int nb = (rem >> 6) & 15;
  int lane = rem & 63;
  const float* W = (rel < R_REL) ? (relw + rel * D * D) : selfw;
  int k0 = kb * 32 + (lane >> 4) * 8;
  int n = nb * 16 + (lane & 15);
  unsigned int o[4];
#pragma unroll
  for (int jj = 0; jj < 4; ++jj) {
    unsigned lo = f2bf(W[(k0 + 2 * jj) * D + n]);
    unsigned hi = f2bf(W[(k0 + 2 * jj + 1) * D + n]);
    o[jj] = lo | (hi << 16);
  }
  ((uint4*)wf)[t] = make_uint4(o[0], o[1], o[2], o[3]);
}

// ---- bias -> B-fragment tile for K=8 presence MFMA ----
__global__ __launch_bounds__(256) void k_cvt_bias(const float* __restrict__ bias,
                                                  unsigned short* __restrict__ bb) {
  int t = blockIdx.x * 256 + threadIdx.x;   // 1024
  int nb = t >> 6, lane = t & 63;
  int lk = lane >> 4, n = nb * 16 + (lane & 15);
  unsigned int o[4];
#pragma unroll
  for (int jj = 0; jj < 4; ++jj) {
    unsigned lo = 0, hi = 0;
    if (lk == 0) {
      lo = f2bf(bias[(2 * jj) * D + n]);
      hi = f2bf(bias[(2 * jj + 1) * D + n]);
    }
    o[jj] = lo | (hi << 16);
  }
  ((uint4*)bb)[t] = make_uint4(o[0], o[1], o[2], o[3]);
}

// ---- histogram over key = r*N + tgt ----
__global__ __launch_bounds__(256) void k_hist(const int* __restrict__ ei,
                                              unsigned* __restrict__ counts) {
  int t = blockIdx.x * 256 + threadIdx.x;
  if (t >= TOT_E) return;
  int r = t / E_EDGE, e = t - r * E_EDGE;
  int tgt = ei[(r * 2 + 1) * E_EDGE + e];
  atomicAdd(&counts[r * N_ENT + tgt], 1u);
}

// ---- exclusive scan (3 kernels) ----
__global__ __launch_bounds__(256) void k_scan1(const unsigned* __restrict__ cnt,
                                               unsigned* __restrict__ off,
                                               unsigned* __restrict__ aux) {
  __shared__ unsigned sc[256];
  int tid = threadIdx.x;
  int base = blockIdx.x * SCAN_B + tid * 4;
  unsigned v[4];
#pragma unroll
  for (int j = 0; j < 4; ++j) v[j] = (base + j < MKEY) ? cnt[base + j] : 0u;
  unsigned s = v[0] + v[1] + v[2] + v[3];
  sc[tid] = s;
  __syncthreads();
  for (int o = 1; o < 256; o <<= 1) {
    unsigned t = (tid >= o) ? sc[tid - o] : 0u;
    __syncthreads();
    sc[tid] += t;
    __syncthreads();
  }
  unsigned excl = sc[tid] - s;
  if (tid == 255) aux[blockIdx.x] = sc[255];
#pragma unroll
  for (int j = 0; j < 4; ++j) {
    if (base + j < MKEY) off[base + j] = excl;
    excl += v[j];
  }
}

__global__ __launch_bounds__(256) void k_scan2(unsigned* __restrict__ aux) {
  __shared__ unsigned sc[256];
  int tid = threadIdx.x;
  int base = tid * 7;
  unsigned v[7];
#pragma unroll
  for (int j = 0; j < 7; ++j) v[j] = (base + j < NBLK_SCAN) ? aux[base + j] : 0u;
  unsigned s = 0;
#pragma unroll
  for (int j = 0; j < 7; ++j) s += v[j];
  sc[tid] = s;
  __syncthreads();
  for (int o = 1; o < 256; o <<= 1) {
    unsigned t = (tid >= o) ? sc[tid - o] : 0u;
    __syncthreads();
    sc[tid] += t;
    __syncthreads();
  }
  unsigned excl = sc[tid] - s;
#pragma unroll
  for (int j = 0; j < 7; ++j) {
    if (base + j < NBLK_SCAN) aux[base + j] = excl;
    excl += v[j];
  }
}

__global__ __launch_bounds__(256) void k_scan3(unsigned* __restrict__ off,
                                               const unsigned* __restrict__ aux) {
  unsigned add = aux[blockIdx.x];
  int base = blockIdx.x * SCAN_B + threadIdx.x * 4;
  if (base + 3 < MKEY) {
    uint4* p = (uint4*)(off + base);
    uint4 x = *p;
    x.x += add; x.y += add; x.z += add; x.w += add;
    *p = x;
  } else {
    for (int j = 0; j < 4; ++j)
      if (base + j < MKEY) off[base + j] += add;
  }
}

// ---- scatter (src | (tgt&63)<<18, ew); off becomes segment ENDs ----
__global__ __launch_bounds__(256) void k_scatter(const int* __restrict__ ei,
                                                 const float* __restrict__ ew,
                                                 unsigned* __restrict__ off,
                                                 unsigned* __restrict__ spack,
                                                 float* __restrict__ sewt) {
  int t = blockIdx.x * 256 + threadIdx.x;
  if (t >= TOT_E) return;
  int r = t / E_EDGE, e = t - r * E_EDGE;
  int tgt = ei[(r * 2 + 1) * E_EDGE + e];
  int src = ei[(r * 2) * E_EDGE + e];
  float w = ew[t];
  unsigned pos = atomicAdd(&off[r * N_ENT + tgt], 1u);
  spack[pos] = (unsigned)src | ((unsigned)(tgt & 63) << 18);
  sewt[pos] = w;
}

// ---- fused main: BARRIER-FREE. 256 thr = 4 independent waves, 32 targets/wave ----
__global__ __launch_bounds__(256, 2) void k_main(const unsigned short* __restrict__ xh,
                                                 const unsigned short* __restrict__ wf,
                                                 const unsigned short* __restrict__ bbf,
                                                 const unsigned* __restrict__ counts,
                                                 const unsigned* __restrict__ off_end,
                                                 const unsigned* __restrict__ spack,
                                                 const float* __restrict__ sewt,
                                                 float* __restrict__ out) {
  __shared__ __align__(16) unsigned char As[4 * 16384];   // per-wave 32x256 bf16, swizzled
  int tid = threadIdx.x;
  int w = tid >> 6, lane = tid & 63;
  int tile = blockIdx.x * 4 + w;
  if (tile >= NTILE) return;                 // no barriers -> safe early exit
  int n0 = tile * 32;
  int lm = lane & 15, lk = lane >> 4;
  unsigned char* Aw = As + w * 16384;        // wave-private tile

  f32x4 acc[2][16] = {};

  // ---- self phase: A-frags direct from global bf16 X ----
  {
    const unsigned short* wfb = wf + 8 * 65536;
#pragma unroll
    for (int kb = 0; kb < 8; ++kb) {
      u16x8 a0 = *(const u16x8*)(xh + (size_t)(n0 + lm) * 256 + kb * 32 + lk * 8);
      u16x8 a1 = *(const u16x8*)(xh + (size_t)(n0 + 16 + lm) * 256 + kb * 32 + lk * 8);
#pragma unroll
      for (int nb = 0; nb < 16; ++nb) {
        u16x8 b = *(const u16x8*)(wfb + ((kb * 16 + nb) * 64 + lane) * 8);
        acc[0][nb] = mfma16(a0, b, acc[0][nb]);
        acc[1][nb] = mfma16(a1, b, acc[1][nb]);
      }
    }
  }

  for (int r = 0; r < 8; ++r) {
    int k0 = r * N_ENT + n0;
    unsigned e0 = off_end[k0 + 31];
    unsigned s0 = off_end[k0] - counts[k0];
    if (s0 == e0) continue;                  // wave-uniform skip (contribution = 0)

    // zero wave tile (16 KB): 16 x b128 per lane
    f32x4 z4 = {0.f, 0.f, 0.f, 0.f};
#pragma unroll
    for (int z = 0; z < 16; ++z)
      *(f32x4*)(Aw + z * 1024 + lane * 16) = z4;

    // run-length aggregation over the sorted contiguous range [s0, e0)
    int g_prev = -1;
    float a0 = 0.f, a1 = 0.f, a2 = 0.f, a3 = 0.f;
    for (unsigned w0 = s0; w0 < e0; w0 += 64) {
      unsigned idx = w0 + (unsigned)lane;
      idx = idx < (unsigned)TOT_E ? idx : (unsigned)(TOT_E - 1);   // clamp (masked later)
      unsigned pkv = spack[idx];
      float wtv = sewt[idx];
      unsigned rem = e0 - w0;
      int m = rem < 64u ? (int)rem : 64;
      for (int grp = 0; grp < m; grp += 8) {
        int gl[8];
        unsigned srcl[8];
        float wtl[8];
#pragma unroll
        for (int u = 0; u < 8; ++u) {
          int uu = grp + u;
          unsigned pk = (unsigned)__shfl((int)pkv, uu);
          float wt = __shfl(wtv, uu);
          bool v = uu < m;
          gl[u] = v ? (int)((pk >> 18) & 31u) : -1;
          unsigned s = pk & 0x3FFFFu;
          srcl[u] = s < (unsigned)N_ENT ? s : 0u;   // clamp garbage (masked anyway)
          wtl[u] = v ? wt : 0.0f;
        }
        ushort4 xv[8];
#pragma unroll
        for (int u = 0; u < 8; ++u)
          xv[u] = *(const ushort4*)(xh + (size_t)srcl[u] * 256 + lane * 4);
#pragma unroll
        for (int u = 0; u < 8; ++u) {
          if (gl[u] >= 0) {
            if (gl[u] != g_prev) {
              if (g_prev >= 0) {   // flush completed row
                unsigned lo = (unsigned)f2bf(a0) | ((unsigned)f2bf(a1) << 16);
                unsigned hi = (unsigned)f2bf(a2) | ((unsigned)f2bf(a3) << 16);
                int wb = (g_prev * 512 + lane * 8) ^ ((g_prev & 7) << 4);
                *(uint2*)(Aw + wb) = make_uint2(lo, hi);
              }
              a0 = a1 = a2 = a3 = 0.f;
              g_prev = gl[u];
            }
            float wt = wtl[u];
            a0 += wt * bf2f(xv[u].x);
            a1 += wt * bf2f(xv[u].y);
            a2 += wt * bf2f(xv[u].z);
            a3 += wt * bf2f(xv[u].w);
          }
        }
      }
    }
    if (g_prev >= 0) {   // final flush
      unsigned lo = (unsigned)f2bf(a0) | ((unsigned)f2bf(a1) << 16);
      unsigned hi = (unsigned)f2bf(a2) | ((unsigned)f2bf(a3) << 16);
      int wb = (g_prev * 512 + lane * 8) ^ ((g_prev & 7) << 4);
      *(uint2*)(Aw + wb) = make_uint2(lo, hi);
    }

    // MFMA from wave tile + wf[r]
    const unsigned short* wfb = wf + r * 65536;
#pragma unroll
    for (int kb = 0; kb < 8; ++kb) {
      int row0 = lm, row1 = 16 + lm;
      u16x8 a0f = *(const u16x8*)(Aw + ((row0 * 512 + kb * 64 + lk * 16) ^ ((row0 & 7) << 4)));
      u16x8 a1f = *(const u16x8*)(Aw + ((row1 * 512 + kb * 64 + lk * 16) ^ ((row1 & 7) << 4)));
#pragma unroll
      for (int nb = 0; nb < 16; ++nb) {
        u16x8 b = *(const u16x8*)(wfb + ((kb * 16 + nb) * 64 + lane) * 8);
        acc[0][nb] = mfma16(a0f, b, acc[0][nb]);
        acc[1][nb] = mfma16(a1f, b, acc[1][nb]);
      }
    }
  }

  // ---- bias via presence MFMA: P[32x8] @ bias[8x256] ----
  {
    u16x8 pa[2] = {};
    if (lk == 0) {
#pragma unroll
      for (int mi = 0; mi < 2; ++mi) {
        int n = n0 + mi * 16 + lm;
#pragma unroll
        for (int r = 0; r < 8; ++r)
          pa[mi][r] = counts[r * N_ENT + n] ? 0x3F80 : 0;
      }
    }
#pragma unroll
    for (int nb = 0; nb < 16; ++nb) {
      u16x8 bb = *(const u16x8*)(bbf + (nb * 64 + lane) * 8);
      acc[0][nb] = mfma16(pa[0], bb, acc[0][nb]);
      acc[1][nb] = mfma16(pa[1], bb, acc[1][nb]);
    }
  }

  // ---- epilogue ----
#pragma unroll
  for (int mi = 0; mi < 2; ++mi)
#pragma unroll
    for (int nb = 0; nb < 16; ++nb) {
      int col = nb * 16 + lm;
#pragma unroll
      for (int j = 0; j < 4; ++j) {
        int row = n0 + mi * 16 + lk * 4 + j;
        out[row * 256 + col] = acc[mi][nb][j];
      }
    }
}

extern "C" void kernel_launch(void* const* d_in, const int* in_sizes, int n_in,
                              void* d_out, int out_size, void* d_ws, size_t ws_size,
                              hipStream_t stream) {
  const float* x = (const float*)d_in[0];
  const float* relw = (const float*)d_in[1];
  const float* selfw = (const float*)d_in[2];
  const float* bias = (const float*)d_in[3];
  const int* ei = (const int*)d_in[4];
  const float* ew = (const float*)d_in[5];
  float* out = (float*)d_out;

  char* ws = (char*)d_ws;
  unsigned short* xh = (unsigned short*)ws;                          // 102,400,000
  unsigned short* wf = (unsigned short*)(ws + 102400000);            //   1,179,648
  unsigned short* bbf = (unsigned short*)(ws + 103579648);           //      16,384
  unsigned* counts = (unsigned*)(ws + 103596032);                    //   6,400,000
  unsigned* offs = (unsigned*)(ws + 109996032);                      //   6,400,000
  unsigned* aux = (unsigned*)(ws + 116396032);                       //       8,192
  unsigned* spack = (unsigned*)(ws + 116404224);                     //   4,800,000
  float* sewt = (float*)(ws + 121204224);                            //   4,800,000

  hipMemsetAsync(counts, 0, (size_t)MKEY * 4, stream);
  k_cvt_x<<<(N_ENT * D) / 2048, 256, 0, stream>>>(x, xh);
  k_cvt_w<<<288, 256, 0, stream>>>(relw, selfw, wf);
  k_cvt_bias<<<4, 256, 0, stream>>>(bias, bbf);
  k_hist<<<(TOT_E + 255) / 256, 256, 0, stream>>>(ei, counts);
  k_scan1<<<NBLK_SCAN, 256, 0, stream>>>(counts, offs, aux);
  k_scan2<<<1, 256, 0, stream>>>(aux);
  k_scan3<<<NBLK_SCAN, 256, 0, stream>>>(offs, aux);
  k_scatter<<<(TOT_E + 255) / 256, 256, 0, stream>>>(ei, ew, offs, spack, sewt);
  k_main<<<(NTILE + 3) / 4, 256, 0, stream>>>(xh, wf, bbf, counts, offs, spack, sewt, out);
}

// Round 9
// 824.845 us; speedup vs baseline: 2.8922x; 1.9535x over previous
//
#include <hip/hip_runtime.h>

// WRGCN: out[t] = sum_r (sum_{e:tgt=t,rel=r} ew_e * X[src_e]) @ W_r + X[t] @ W_self + P @ bias
// Counting-sort edges by key = r*N + tgt. k_main: 512 thr / 64 targets; wave w owns keys
// [n0+8w, n0+8w+8) whose edges are ONE contiguous sorted range; compacted walk with
// one-instruction row gathers (8 in flight), run-length f32 register accumulation flushed
// as bf16 into the swizzled As tile; then r6-proven MFMA / bias / epilogue.

#define N_ENT 200000
#define D 256
#define R_REL 8
#define E_EDGE 150000
#define TOT_E (R_REL * E_EDGE)        // 1,200,000
#define MKEY (N_ENT * R_REL)          // 1,600,000
#define SCAN_B 1024
#define NBLK_SCAN ((MKEY + SCAN_B - 1) / SCAN_B)   // 1563

typedef __bf16 bf16x8 __attribute__((ext_vector_type(8)));
typedef unsigned short u16x8 __attribute__((ext_vector_type(8)));
typedef float f32x4 __attribute__((ext_vector_type(4)));

__device__ __forceinline__ unsigned short f2bf(float f) {
  unsigned int u = __builtin_bit_cast(unsigned int, f);
  u += 0x7FFFu + ((u >> 16) & 1u);   // RNE (inputs finite)
  return (unsigned short)(u >> 16);
}
__device__ __forceinline__ float bf2f(unsigned short u) {
  return __builtin_bit_cast(float, ((unsigned)u) << 16);
}
__device__ __forceinline__ f32x4 mfma16(u16x8 a, u16x8 b, f32x4 c) {
  return __builtin_amdgcn_mfma_f32_16x16x32_bf16(
      __builtin_bit_cast(bf16x8, a), __builtin_bit_cast(bf16x8, b), c, 0, 0, 0);
}

// ---- X (f32) -> Xh (bf16) ----
__global__ __launch_bounds__(256) void k_cvt_x(const float* __restrict__ x,
                                               unsigned short* __restrict__ xh) {
  int i = blockIdx.x * 256 + threadIdx.x;
  const float4* xv = (const float4*)x;
  float4 a = xv[2 * i], b = xv[2 * i + 1];
  uint4 o;
  o.x = (unsigned)f2bf(a.x) | ((unsigned)f2bf(a.y) << 16);
  o.y = (unsigned)f2bf(a.z) | ((unsigned)f2bf(a.w) << 16);
  o.z = (unsigned)f2bf(b.x) | ((unsigned)f2bf(b.y) << 16);
  o.w = (unsigned)f2bf(b.z) | ((unsigned)f2bf(b.w) << 16);
  ((uint4*)xh)[i] = o;
}

// ---- Weights -> bf16 MFMA B-fragment order. tile 0..7 = W_r, 8 = self ----
__global__ __launch_bounds__(256) void k_cvt_w(const float* __restrict__ relw,
                                               const float* __restrict__ selfw,
                                               unsigned short* __restrict__ wf) {
  int t = blockIdx.x * 256 + threadIdx.x;   // 9*8*16*64 = 73728
  int rel = t >> 13;
  int rem = t & 8191;
  int kb = rem >> 10;
  int nb = (rem >> 6) & 15;
  int lane = rem & 63;
  const float* W = (rel < R_REL) ? (relw + rel * D * D) : selfw;
  int k0 = kb * 32 + (lane >> 4) * 8;
  int n = nb * 16 + (lane & 15);
  unsigned int o[4];
#pragma unroll
  for (int jj = 0; jj < 4; ++jj) {
    unsigned lo = f2bf(W[(k0 + 2 * jj) * D + n]);
    unsigned hi = f2bf(W[(k0 + 2 * jj + 1) * D + n]);
    o[jj] = lo | (hi << 16);
  }
  ((uint4*)wf)[t] = make_uint4(o[0], o[1], o[2], o[3]);
}

// ---- bias -> B-fragment tile for K=8 presence MFMA ----
__global__ __launch_bounds__(256) void k_cvt_bias(const float* __restrict__ bias,
                                                  unsigned short* __restrict__ bb) {
  int t = blockIdx.x * 256 + threadIdx.x;   // 1024
  int nb = t >> 6, lane = t & 63;
  int lk = lane >> 4, n = nb * 16 + (lane & 15);
  unsigned int o[4];
#pragma unroll
  for (int jj = 0; jj < 4; ++jj) {
    unsigned lo = 0, hi = 0;
    if (lk == 0) {
      lo = f2bf(bias[(2 * jj) * D + n]);
      hi = f2bf(bias[(2 * jj + 1) * D + n]);
    }
    o[jj] = lo | (hi << 16);
  }
  ((uint4*)bb)[t] = make_uint4(o[0], o[1], o[2], o[3]);
}

// ---- histogram over key = r*N + tgt ----
__global__ __launch_bounds__(256) void k_hist(const int* __restrict__ ei,
                                              unsigned* __restrict__ counts) {
  int t = blockIdx.x * 256 + threadIdx.x;
  if (t >= TOT_E) return;
  int r = t / E_EDGE, e = t - r * E_EDGE;
  int tgt = ei[(r * 2 + 1) * E_EDGE + e];
  atomicAdd(&counts[r * N_ENT + tgt], 1u);
}

// ---- exclusive scan (3 kernels) ----
__global__ __launch_bounds__(256) void k_scan1(const unsigned* __restrict__ cnt,
                                               unsigned* __restrict__ off,
                                               unsigned* __restrict__ aux) {
  __shared__ unsigned sc[256];
  int tid = threadIdx.x;
  int base = blockIdx.x * SCAN_B + tid * 4;
  unsigned v[4];
#pragma unroll
  for (int j = 0; j < 4; ++j) v[j] = (base + j < MKEY) ? cnt[base + j] : 0u;
  unsigned s = v[0] + v[1] + v[2] + v[3];
  sc[tid] = s;
  __syncthreads();
  for (int o = 1; o < 256; o <<= 1) {
    unsigned t = (tid >= o) ? sc[tid - o] : 0u;
    __syncthreads();
    sc[tid] += t;
    __syncthreads();
  }
  unsigned excl = sc[tid] - s;
  if (tid == 255) aux[blockIdx.x] = sc[255];
#pragma unroll
  for (int j = 0; j < 4; ++j) {
    if (base + j < MKEY) off[base + j] = excl;
    excl += v[j];
  }
}

__global__ __launch_bounds__(256) void k_scan2(unsigned* __restrict__ aux) {
  __shared__ unsigned sc[256];
  int tid = threadIdx.x;
  int base = tid * 7;
  unsigned v[7];
#pragma unroll
  for (int j = 0; j < 7; ++j) v[j] = (base + j < NBLK_SCAN) ? aux[base + j] : 0u;
  unsigned s = 0;
#pragma unroll
  for (int j = 0; j < 7; ++j) s += v[j];
  sc[tid] = s;
  __syncthreads();
  for (int o = 1; o < 256; o <<= 1) {
    unsigned t = (tid >= o) ? sc[tid - o] : 0u;
    __syncthreads();
    sc[tid] += t;
    __syncthreads();
  }
  unsigned excl = sc[tid] - s;
#pragma unroll
  for (int j = 0; j < 7; ++j) {
    if (base + j < NBLK_SCAN) aux[base + j] = excl;
    excl += v[j];
  }
}

__global__ __launch_bounds__(256) void k_scan3(unsigned* __restrict__ off,
                                               const unsigned* __restrict__ aux) {
  unsigned add = aux[blockIdx.x];
  int base = blockIdx.x * SCAN_B + threadIdx.x * 4;
  if (base + 3 < MKEY) {
    uint4* p = (uint4*)(off + base);
    uint4 x = *p;
    x.x += add; x.y += add; x.z += add; x.w += add;
    *p = x;
  } else {
    for (int j = 0; j < 4; ++j)
      if (base + j < MKEY) off[base + j] += add;
  }
}

// ---- scatter (src | (tgt&63)<<18, ew); off becomes segment ENDs ----
__global__ __launch_bounds__(256) void k_scatter(const int* __restrict__ ei,
                                                 const float* __restrict__ ew,
                                                 unsigned* __restrict__ off,
                                                 unsigned* __restrict__ spack,
                                                 float* __restrict__ sewt) {
  int t = blockIdx.x * 256 + threadIdx.x;
  if (t >= TOT_E) return;
  int r = t / E_EDGE, e = t - r * E_EDGE;
  int tgt = ei[(r * 2 + 1) * E_EDGE + e];
  int src = ei[(r * 2) * E_EDGE + e];
  float w = ew[t];
  unsigned pos = atomicAdd(&off[r * N_ENT + tgt], 1u);
  spack[pos] = (unsigned)src | ((unsigned)(tgt & 63) << 18);
  sewt[pos] = w;
}

// ---- fused main: 512 threads, 64 targets/block, wave w owns keys [8w, 8w+8) ----
__global__ __launch_bounds__(512, 2) void k_main(const unsigned short* __restrict__ xh,
                                                 const unsigned short* __restrict__ wf,
                                                 const unsigned short* __restrict__ bbf,
                                                 const unsigned* __restrict__ counts,
                                                 const unsigned* __restrict__ off_end,
                                                 const unsigned* __restrict__ spack,
                                                 const float* __restrict__ sewt,
                                                 float* __restrict__ out) {
  __shared__ __align__(16) unsigned char As[64 * 512];   // 64x256 bf16 tile, XOR-swizzled
  int n0 = blockIdx.x * 64;
  int tid = threadIdx.x;
  int w = tid >> 6, lane = tid & 63;
  int lm = lane & 15, lk = lane >> 4;
  int rbase = (w >> 2) * 32;          // wave's 32-row half for MFMA
  int cbase = (w & 3) * 4;            // wave's 4 nb columns (64 cols)

  f32x4 acc[2][4] = {};

  // ---- self phase: A-frags direct from global bf16 X ----
  {
    const unsigned short* wfb = wf + 8 * 65536;
#pragma unroll
    for (int kb = 0; kb < 8; ++kb) {
      u16x8 a[2], b[4];
#pragma unroll
      for (int mi = 0; mi < 2; ++mi)
        a[mi] = *(const u16x8*)(xh + (size_t)(n0 + rbase + mi * 16 + lm) * 256 + kb * 32 + lk * 8);
#pragma unroll
      for (int ni = 0; ni < 4; ++ni)
        b[ni] = *(const u16x8*)(wfb + ((kb * 16 + cbase + ni) * 64 + lane) * 8);
#pragma unroll
      for (int mi = 0; mi < 2; ++mi)
#pragma unroll
        for (int ni = 0; ni < 4; ++ni)
          acc[mi][ni] = mfma16(a[mi], b[ni], acc[mi][ni]);
    }
  }

  for (int r = 0; r < 8; ++r) {
    // wave's 8 keys = one contiguous sorted edge range
    int kbase = r * N_ENT + n0 + w * 8;
    unsigned cA = counts[kbase];
    unsigned sBeg = off_end[kbase] - cA;
    unsigned eEnd = off_end[kbase + 7];

    // zero my 8 rows (empty keys stay zero; flushes overwrite, same-lane ordered)
#pragma unroll
    for (int k = 0; k < 8; ++k) {
      int g = w * 8 + k;
      int wb = (g * 512 + lane * 8) ^ ((g & 7) << 4);
      *(uint2*)(As + wb) = make_uint2(0u, 0u);
    }

    // compacted run-length aggregation; lane l holds cols 4l..4l+3
    int gp = -1;
    float a0 = 0.f, a1 = 0.f, a2 = 0.f, a3 = 0.f;
    for (unsigned chunk = sBeg; chunk < eEnd; chunk += 64u) {
      unsigned idx = chunk + (unsigned)lane;
      if (idx >= (unsigned)TOT_E) idx = (unsigned)(TOT_E - 1);
      unsigned pkv = spack[idx];
      float wtv = sewt[idx];
      unsigned rem = eEnd - chunk;
      int m = rem < 64u ? (int)rem : 64;
      for (int g8 = 0; g8 < m; g8 += 8) {
        unsigned pk8[8];
        float wt8[8];
#pragma unroll
        for (int u = 0; u < 8; ++u) {
          pk8[u] = (unsigned)__shfl((int)pkv, g8 + u);
          wt8[u] = __shfl(wtv, g8 + u);
        }
        ushort4 xv[8];
#pragma unroll
        for (int u = 0; u < 8; ++u) {
          unsigned srcu = (g8 + u < m) ? (pk8[u] & 0x3FFFFu) : 0u;  // invalid -> row 0 (L1-hot)
          xv[u] = *(const ushort4*)(xh + (size_t)srcu * 256 + lane * 4);
        }
#pragma unroll
        for (int u = 0; u < 8; ++u) {
          if (g8 + u < m) {            // wave-uniform
            int g = (int)(pk8[u] >> 18);
            if (g != gp) {             // sorted keys -> run-length flush
              if (gp >= 0) {
                unsigned lo = (unsigned)f2bf(a0) | ((unsigned)f2bf(a1) << 16);
                unsigned hi = (unsigned)f2bf(a2) | ((unsigned)f2bf(a3) << 16);
                int wb = (gp * 512 + lane * 8) ^ ((gp & 7) << 4);
                *(uint2*)(As + wb) = make_uint2(lo, hi);
              }
              a0 = a1 = a2 = a3 = 0.f;
              gp = g;
            }
            float wt = wt8[u];
            a0 += wt * bf2f(xv[u].x);
            a1 += wt * bf2f(xv[u].y);
            a2 += wt * bf2f(xv[u].z);
            a3 += wt * bf2f(xv[u].w);
          }
        }
      }
    }
    if (gp >= 0) {   // final flush
      unsigned lo = (unsigned)f2bf(a0) | ((unsigned)f2bf(a1) << 16);
      unsigned hi = (unsigned)f2bf(a2) | ((unsigned)f2bf(a3) << 16);
      int wb = (gp * 512 + lane * 8) ^ ((gp & 7) << 4);
      *(uint2*)(As + wb) = make_uint2(lo, hi);
    }
    __syncthreads();

    // ---- MFMA from As + wf[r] (r6-proven) ----
    const unsigned short* wfb = wf + r * 65536;
#pragma unroll
    for (int kb = 0; kb < 8; ++kb) {
      u16x8 a[2], b[4];
#pragma unroll
      for (int mi = 0; mi < 2; ++mi) {
        int row = rbase + mi * 16 + lm;
        int byt = (row * 512 + kb * 64 + lk * 16) ^ ((row & 7) << 4);
        a[mi] = *(const u16x8*)(As + byt);
      }
#pragma unroll
      for (int ni = 0; ni < 4; ++ni)
        b[ni] = *(const u16x8*)(wfb + ((kb * 16 + cbase + ni) * 64 + lane) * 8);
#pragma unroll
      for (int mi = 0; mi < 2; ++mi)
#pragma unroll
        for (int ni = 0; ni < 4; ++ni)
          acc[mi][ni] = mfma16(a[mi], b[ni], acc[mi][ni]);
    }
    __syncthreads();
  }

  // ---- bias via presence MFMA: P[64x8] @ bias[8x256] ----
  {
    u16x8 bb[4];
#pragma unroll
    for (int ni = 0; ni < 4; ++ni)
      bb[ni] = *(const u16x8*)(bbf + ((cbase + ni) * 64 + lane) * 8);
#pragma unroll
    for (int mi = 0; mi < 2; ++mi) {
      u16x8 pa = {};
      if (lk == 0) {
        int n = n0 + rbase + mi * 16 + lm;
#pragma unroll
        for (int r = 0; r < 8; ++r)
          pa[r] = counts[r * N_ENT + n] ? 0x3F80 : 0;
      }
#pragma unroll
      for (int ni = 0; ni < 4; ++ni)
        acc[mi][ni] = mfma16(pa, bb[ni], acc[mi][ni]);
    }
  }

  // ---- epilogue ----
#pragma unroll
  for (int mi = 0; mi < 2; ++mi)
#pragma unroll
    for (int ni = 0; ni < 4; ++ni) {
      int col = (w & 3) * 64 + ni * 16 + lm;
#pragma unroll
      for (int j = 0; j < 4; ++j) {
        int row = n0 + rbase + mi * 16 + lk * 4 + j;
        out[row * 256 + col] = acc[mi][ni][j];
      }
    }
}

extern "C" void kernel_launch(void* const* d_in, const int* in_sizes, int n_in,
                              void* d_out, int out_size, void* d_ws, size_t ws_size,
                              hipStream_t stream) {
  const float* x = (const float*)d_in[0];
  const float* relw = (const float*)d_in[1];
  const float* selfw = (const float*)d_in[2];
  const float* bias = (const float*)d_in[3];
  const int* ei = (const int*)d_in[4];
  const float* ew = (const float*)d_in[5];
  float* out = (float*)d_out;

  char* ws = (char*)d_ws;
  unsigned short* xh = (unsigned short*)ws;                          // 102,400,000
  unsigned short* wf = (unsigned short*)(ws + 102400000);            //   1,179,648
  unsigned short* bbf = (unsigned short*)(ws + 103579648);           //      16,384
  unsigned* counts = (unsigned*)(ws + 103596032);                    //   6,400,000
  unsigned* offs = (unsigned*)(ws + 109996032);                      //   6,400,000
  unsigned* aux = (unsigned*)(ws + 116396032);                       //       8,192
  unsigned* spack = (unsigned*)(ws + 116404224);                     //   4,800,000
  float* sewt = (float*)(ws + 121204224);                            //   4,800,000

  hipMemsetAsync(counts, 0, (size_t)MKEY * 4, stream);
  k_cvt_x<<<(N_ENT * D) / 2048, 256, 0, stream>>>(x, xh);
  k_cvt_w<<<288, 256, 0, stream>>>(relw, selfw, wf);
  k_cvt_bias<<<4, 256, 0, stream>>>(bias, bbf);
  k_hist<<<(TOT_E + 255) / 256, 256, 0, stream>>>(ei, counts);
  k_scan1<<<NBLK_SCAN, 256, 0, stream>>>(counts, offs, aux);
  k_scan2<<<1, 256, 0, stream>>>(aux);
  k_scan3<<<NBLK_SCAN, 256, 0, stream>>>(offs, aux);
  k_scatter<<<(TOT_E + 255) / 256, 256, 0, stream>>>(ei, ew, offs, spack, sewt);
  k_main<<<N_ENT / 64, 512, 0, stream>>>(xh, wf, bbf, counts, offs, spack, sewt, out);
}

// Round 10
// 788.996 us; speedup vs baseline: 3.0236x; 1.0454x over previous
//
#include <hip/hip_runtime.h>

// WRGCN: out[t] = sum_r (sum_{e:tgt=t,rel=r} ew_e * X[src_e]) @ W_r + X[t] @ W_self + P @ bias
// Counting-sort edges by key = r*N + tgt. k_main: 512 thr / 64 targets; wave w owns keys
// [n0+8w, n0+8w+8). ALL rels' meta (segment bounds via off_end[k-1]) and first 64-edge
// chunks are prefetched at block start (2 latency quanta total); the fully-unrolled rel
// loop then only pays gather latency, overlapped across waves. r9-proven MFMA/bias/epilogue.

#define N_ENT 200000
#define D 256
#define R_REL 8
#define E_EDGE 150000
#define TOT_E (R_REL * E_EDGE)        // 1,200,000
#define MKEY (N_ENT * R_REL)          // 1,600,000
#define SCAN_B 1024
#define NBLK_SCAN ((MKEY + SCAN_B - 1) / SCAN_B)   // 1563

typedef __bf16 bf16x8 __attribute__((ext_vector_type(8)));
typedef unsigned short u16x8 __attribute__((ext_vector_type(8)));
typedef float f32x4 __attribute__((ext_vector_type(4)));

__device__ __forceinline__ unsigned short f2bf(float f) {
  unsigned int u = __builtin_bit_cast(unsigned int, f);
  u += 0x7FFFu + ((u >> 16) & 1u);   // RNE (inputs finite)
  return (unsigned short)(u >> 16);
}
__device__ __forceinline__ float bf2f(unsigned short u) {
  return __builtin_bit_cast(float, ((unsigned)u) << 16);
}
__device__ __forceinline__ f32x4 mfma16(u16x8 a, u16x8 b, f32x4 c) {
  return __builtin_amdgcn_mfma_f32_16x16x32_bf16(
      __builtin_bit_cast(bf16x8, a), __builtin_bit_cast(bf16x8, b), c, 0, 0, 0);
}

// ---- X (f32) -> Xh (bf16) ----
__global__ __launch_bounds__(256) void k_cvt_x(const float* __restrict__ x,
                                               unsigned short* __restrict__ xh) {
  int i = blockIdx.x * 256 + threadIdx.x;
  const float4* xv = (const float4*)x;
  float4 a = xv[2 * i], b = xv[2 * i + 1];
  uint4 o;
  o.x = (unsigned)f2bf(a.x) | ((unsigned)f2bf(a.y) << 16);
  o.y = (unsigned)f2bf(a.z) | ((unsigned)f2bf(a.w) << 16);
  o.z = (unsigned)f2bf(b.x) | ((unsigned)f2bf(b.y) << 16);
  o.w = (unsigned)f2bf(b.z) | ((unsigned)f2bf(b.w) << 16);
  ((uint4*)xh)[i] = o;
}

// ---- Weights -> bf16 MFMA B-fragment order. tile 0..7 = W_r, 8 = self ----
__global__ __launch_bounds__(256) void k_cvt_w(const float* __restrict__ relw,
                                               const float* __restrict__ selfw,
                                               unsigned short* __restrict__ wf) {
  int t = blockIdx.x * 256 + threadIdx.x;   // 9*8*16*64 = 73728
  int rel = t >> 13;
  int rem = t & 8191;
  int kb = rem >> 10;
  int nb = (rem >> 6) & 15;
  int lane = rem & 63;
  const float* W = (rel < R_REL) ? (relw + rel * D * D) : selfw;
  int k0 = kb * 32 + (lane >> 4) * 8;
  int n = nb * 16 + (lane & 15);
  unsigned int o[4];
#pragma unroll
  for (int jj = 0; jj < 4; ++jj) {
    unsigned lo = f2bf(W[(k0 + 2 * jj) * D + n]);
    unsigned hi = f2bf(W[(k0 + 2 * jj + 1) * D + n]);
    o[jj] = lo | (hi << 16);
  }
  ((uint4*)wf)[t] = make_uint4(o[0], o[1], o[2], o[3]);
}

// ---- bias -> B-fragment tile for K=8 presence MFMA ----
__global__ __launch_bounds__(256) void k_cvt_bias(const float* __restrict__ bias,
                                                  unsigned short* __restrict__ bb) {
  int t = blockIdx.x * 256 + threadIdx.x;   // 1024
  int nb = t >> 6, lane = t & 63;
  int lk = lane >> 4, n = nb * 16 + (lane & 15);
  unsigned int o[4];
#pragma unroll
  for (int jj = 0; jj < 4; ++jj) {
    unsigned lo = 0, hi = 0;
    if (lk == 0) {
      lo = f2bf(bias[(2 * jj) * D + n]);
      hi = f2bf(bias[(2 * jj + 1) * D + n]);
    }
    o[jj] = lo | (hi << 16);
  }
  ((uint4*)bb)[t] = make_uint4(o[0], o[1], o[2], o[3]);
}

// ---- histogram over key = r*N + tgt ----
__global__ __launch_bounds__(256) void k_hist(const int* __restrict__ ei,
                                              unsigned* __restrict__ counts) {
  int t = blockIdx.x * 256 + threadIdx.x;
  if (t >= TOT_E) return;
  int r = t / E_EDGE, e = t - r * E_EDGE;
  int tgt = ei[(r * 2 + 1) * E_EDGE + e];
  atomicAdd(&counts[r * N_ENT + tgt], 1u);
}

// ---- exclusive scan (3 kernels) ----
__global__ __launch_bounds__(256) void k_scan1(const unsigned* __restrict__ cnt,
                                               unsigned* __restrict__ off,
                                               unsigned* __restrict__ aux) {
  __shared__ unsigned sc[256];
  int tid = threadIdx.x;
  int base = blockIdx.x * SCAN_B + tid * 4;
  unsigned v[4];
#pragma unroll
  for (int j = 0; j < 4; ++j) v[j] = (base + j < MKEY) ? cnt[base + j] : 0u;
  unsigned s = v[0] + v[1] + v[2] + v[3];
  sc[tid] = s;
  __syncthreads();
  for (int o = 1; o < 256; o <<= 1) {
    unsigned t = (tid >= o) ? sc[tid - o] : 0u;
    __syncthreads();
    sc[tid] += t;
    __syncthreads();
  }
  unsigned excl = sc[tid] - s;
  if (tid == 255) aux[blockIdx.x] = sc[255];
#pragma unroll
  for (int j = 0; j < 4; ++j) {
    if (base + j < MKEY) off[base + j] = excl;
    excl += v[j];
  }
}

__global__ __launch_bounds__(256) void k_scan2(unsigned* __restrict__ aux) {
  __shared__ unsigned sc[256];
  int tid = threadIdx.x;
  int base = tid * 7;
  unsigned v[7];
#pragma unroll
  for (int j = 0; j < 7; ++j) v[j] = (base + j < NBLK_SCAN) ? aux[base + j] : 0u;
  unsigned s = 0;
#pragma unroll
  for (int j = 0; j < 7; ++j) s += v[j];
  sc[tid] = s;
  __syncthreads();
  for (int o = 1; o < 256; o <<= 1) {
    unsigned t = (tid >= o) ? sc[tid - o] : 0u;
    __syncthreads();
    sc[tid] += t;
    __syncthreads();
  }
  unsigned excl = sc[tid] - s;
#pragma unroll
  for (int j = 0; j < 7; ++j) {
    if (base + j < NBLK_SCAN) aux[base + j] = excl;
    excl += v[j];
  }
}

__global__ __launch_bounds__(256) void k_scan3(unsigned* __restrict__ off,
                                               const unsigned* __restrict__ aux) {
  unsigned add = aux[blockIdx.x];
  int base = blockIdx.x * SCAN_B + threadIdx.x * 4;
  if (base + 3 < MKEY) {
    uint4* p = (uint4*)(off + base);
    uint4 x = *p;
    x.x += add; x.y += add; x.z += add; x.w += add;
    *p = x;
  } else {
    for (int j = 0; j < 4; ++j)
      if (base + j < MKEY) off[base + j] += add;
  }
}

// ---- scatter (src | (tgt&63)<<18, ew); off becomes segment ENDs ----
__global__ __launch_bounds__(256) void k_scatter(const int* __restrict__ ei,
                                                 const float* __restrict__ ew,
                                                 unsigned* __restrict__ off,
                                                 unsigned* __restrict__ spack,
                                                 float* __restrict__ sewt) {
  int t = blockIdx.x * 256 + threadIdx.x;
  if (t >= TOT_E) return;
  int r = t / E_EDGE, e = t - r * E_EDGE;
  int tgt = ei[(r * 2 + 1) * E_EDGE + e];
  int src = ei[(r * 2) * E_EDGE + e];
  float w = ew[t];
  unsigned pos = atomicAdd(&off[r * N_ENT + tgt], 1u);
  spack[pos] = (unsigned)src | ((unsigned)(tgt & 63) << 18);
  sewt[pos] = w;
}

// ---- fused main: 512 threads, 64 targets/block, wave w owns keys [8w, 8w+8) ----
__global__ __launch_bounds__(512, 2) void k_main(const unsigned short* __restrict__ xh,
                                                 const unsigned short* __restrict__ wf,
                                                 const unsigned short* __restrict__ bbf,
                                                 const unsigned* __restrict__ counts,
                                                 const unsigned* __restrict__ off_end,
                                                 const unsigned* __restrict__ spack,
                                                 const float* __restrict__ sewt,
                                                 float* __restrict__ out) {
  __shared__ __align__(16) unsigned char As[64 * 512];   // 64x256 bf16 tile, XOR-swizzled
  int n0 = blockIdx.x * 64;
  int tid = threadIdx.x;
  int w = tid >> 6, lane = tid & 63;
  int lm = lane & 15, lk = lane >> 4;
  int rbase = (w >> 2) * 32;          // wave's 32-row half for MFMA
  int cbase = (w & 3) * 4;            // wave's 4 nb columns (64 cols)

  // ---- prefetch 1: all 8 rels' segment bounds (16 independent loads) ----
  // segments are contiguous in sorted order: start(key k) = end(key k-1)
  unsigned sB[8], eE[8];
#pragma unroll
  for (int r = 0; r < 8; ++r) {
    int kb2 = r * N_ENT + n0 + w * 8;
    sB[r] = kb2 ? off_end[kb2 - 1] : 0u;
    eE[r] = off_end[kb2 + 7];
  }
  // ---- prefetch 2: first 64-edge chunk per rel (16 independent loads) ----
  unsigned pk0[8];
  float wt0[8];
#pragma unroll
  for (int r = 0; r < 8; ++r) {
    unsigned idx = sB[r] + (unsigned)lane;
    if (idx >= (unsigned)TOT_E) idx = (unsigned)(TOT_E - 1);
    pk0[r] = spack[idx];
    wt0[r] = sewt[idx];
  }

  f32x4 acc[2][4] = {};

  // ---- self phase: A-frags direct from global bf16 X ----
  {
    const unsigned short* wfb = wf + 8 * 65536;
#pragma unroll
    for (int kb = 0; kb < 8; ++kb) {
      u16x8 a[2], b[4];
#pragma unroll
      for (int mi = 0; mi < 2; ++mi)
        a[mi] = *(const u16x8*)(xh + (size_t)(n0 + rbase + mi * 16 + lm) * 256 + kb * 32 + lk * 8);
#pragma unroll
      for (int ni = 0; ni < 4; ++ni)
        b[ni] = *(const u16x8*)(wfb + ((kb * 16 + cbase + ni) * 64 + lane) * 8);
#pragma unroll
      for (int mi = 0; mi < 2; ++mi)
#pragma unroll
        for (int ni = 0; ni < 4; ++ni)
          acc[mi][ni] = mfma16(a[mi], b[ni], acc[mi][ni]);
    }
  }

#pragma unroll
  for (int r = 0; r < 8; ++r) {
    // zero my 8 rows (empty keys stay zero; flushes overwrite, same-lane ordered)
#pragma unroll
    for (int k = 0; k < 8; ++k) {
      int g = w * 8 + k;
      int wb = (g * 512 + lane * 8) ^ ((g & 7) << 4);
      *(uint2*)(As + wb) = make_uint2(0u, 0u);
    }

    unsigned s0 = sB[r], e0 = eE[r];
    int gp = -1;
    float a0 = 0.f, a1 = 0.f, a2 = 0.f, a3 = 0.f;
    unsigned pkv = pk0[r];
    float wtv = wt0[r];
    for (unsigned chunk = s0; chunk < e0; chunk += 64u) {
      if (chunk != s0) {                 // rare: range > 64 edges
        unsigned idx = chunk + (unsigned)lane;
        if (idx >= (unsigned)TOT_E) idx = (unsigned)(TOT_E - 1);
        pkv = spack[idx];
        wtv = sewt[idx];
      }
      unsigned rem = e0 - chunk;
      int m = rem < 64u ? (int)rem : 64;
      for (int g8 = 0; g8 < m; g8 += 8) {
        unsigned pk8[8];
        float wt8[8];
#pragma unroll
        for (int u = 0; u < 8; ++u) {
          pk8[u] = (unsigned)__shfl((int)pkv, g8 + u);
          wt8[u] = __shfl(wtv, g8 + u);
        }
        ushort4 xv[8];
#pragma unroll
        for (int u = 0; u < 8; ++u) {
          unsigned srcu = (g8 + u < m) ? (pk8[u] & 0x3FFFFu) : 0u;  // invalid -> row 0 (L1-hot)
          xv[u] = *(const ushort4*)(xh + (size_t)srcu * 256 + lane * 4);
        }
#pragma unroll
        for (int u = 0; u < 8; ++u) {
          if (g8 + u < m) {            // wave-uniform
            int g = (int)(pk8[u] >> 18);
            if (g != gp) {             // sorted keys -> run-length flush
              if (gp >= 0) {
                unsigned lo = (unsigned)f2bf(a0) | ((unsigned)f2bf(a1) << 16);
                unsigned hi = (unsigned)f2bf(a2) | ((unsigned)f2bf(a3) << 16);
                int wb = (gp * 512 + lane * 8) ^ ((gp & 7) << 4);
                *(uint2*)(As + wb) = make_uint2(lo, hi);
              }
              a0 = a1 = a2 = a3 = 0.f;
              gp = g;
            }
            float wt = wt8[u];
            a0 += wt * bf2f(xv[u].x);
            a1 += wt * bf2f(xv[u].y);
            a2 += wt * bf2f(xv[u].z);
            a3 += wt * bf2f(xv[u].w);
          }
        }
      }
    }
    if (gp >= 0) {   // final flush
      unsigned lo = (unsigned)f2bf(a0) | ((unsigned)f2bf(a1) << 16);
      unsigned hi = (unsigned)f2bf(a2) | ((unsigned)f2bf(a3) << 16);
      int wb = (gp * 512 + lane * 8) ^ ((gp & 7) << 4);
      *(uint2*)(As + wb) = make_uint2(lo, hi);
    }
    __syncthreads();

    // ---- MFMA from As + wf[r] ----
    const unsigned short* wfb = wf + r * 65536;
#pragma unroll
    for (int kb = 0; kb < 8; ++kb) {
      u16x8 a[2], b[4];
#pragma unroll
      for (int mi = 0; mi < 2; ++mi) {
        int row = rbase + mi * 16 + lm;
        int byt = (row * 512 + kb * 64 + lk * 16) ^ ((row & 7) << 4);
        a[mi] = *(const u16x8*)(As + byt);
      }
#pragma unroll
      for (int ni = 0; ni < 4; ++ni)
        b[ni] = *(const u16x8*)(wfb + ((kb * 16 + cbase + ni) * 64 + lane) * 8);
#pragma unroll
      for (int mi = 0; mi < 2; ++mi)
#pragma unroll
        for (int ni = 0; ni < 4; ++ni)
          acc[mi][ni] = mfma16(a[mi], b[ni], acc[mi][ni]);
    }
    __syncthreads();
  }

  // ---- bias via presence MFMA: P[64x8] @ bias[8x256] ----
  {
    u16x8 bb[4];
#pragma unroll
    for (int ni = 0; ni < 4; ++ni)
      bb[ni] = *(const u16x8*)(bbf + ((cbase + ni) * 64 + lane) * 8);
#pragma unroll
    for (int mi = 0; mi < 2; ++mi) {
      u16x8 pa = {};
      if (lk == 0) {
        int n = n0 + rbase + mi * 16 + lm;
#pragma unroll
        for (int r = 0; r < 8; ++r)
          pa[r] = counts[r * N_ENT + n] ? 0x3F80 : 0;
      }
#pragma unroll
      for (int ni = 0; ni < 4; ++ni)
        acc[mi][ni] = mfma16(pa, bb[ni], acc[mi][ni]);
    }
  }

  // ---- epilogue ----
#pragma unroll
  for (int mi = 0; mi < 2; ++mi)
#pragma unroll
    for (int ni = 0; ni < 4; ++ni) {
      int col = (w & 3) * 64 + ni * 16 + lm;
#pragma unroll
      for (int j = 0; j < 4; ++j) {
        int row = n0 + rbase + mi * 16 + lk * 4 + j;
        out[row * 256 + col] = acc[mi][ni][j];
      }
    }
}

extern "C" void kernel_launch(void* const* d_in, const int* in_sizes, int n_in,
                              void* d_out, int out_size, void* d_ws, size_t ws_size,
                              hipStream_t stream) {
  const float* x = (const float*)d_in[0];
  const float* relw = (const float*)d_in[1];
  const float* selfw = (const float*)d_in[2];
  const float* bias = (const float*)d_in[3];
  const int* ei = (const int*)d_in[4];
  const float* ew = (const float*)d_in[5];
  float* out = (float*)d_out;

  char* ws = (char*)d_ws;
  unsigned short* xh = (unsigned short*)ws;                          // 102,400,000
  unsigned short* wf = (unsigned short*)(ws + 102400000);            //   1,179,648
  unsigned short* bbf = (unsigned short*)(ws + 103579648);           //      16,384
  unsigned* counts = (unsigned*)(ws + 103596032);                    //   6,400,000
  unsigned* offs = (unsigned*)(ws + 109996032);                      //   6,400,000
  unsigned* aux = (unsigned*)(ws + 116396032);                       //       8,192
  unsigned* spack = (unsigned*)(ws + 116404224);                     //   4,800,000
  float* sewt = (float*)(ws + 121204224);                            //   4,800,000

  hipMemsetAsync(counts, 0, (size_t)MKEY * 4, stream);
  k_cvt_x<<<(N_ENT * D) / 2048, 256, 0, stream>>>(x, xh);
  k_cvt_w<<<288, 256, 0, stream>>>(relw, selfw, wf);
  k_cvt_bias<<<4, 256, 0, stream>>>(bias, bbf);
  k_hist<<<(TOT_E + 255) / 256, 256, 0, stream>>>(ei, counts);
  k_scan1<<<NBLK_SCAN, 256, 0, stream>>>(counts, offs, aux);
  k_scan2<<<1, 256, 0, stream>>>(aux);
  k_scan3<<<NBLK_SCAN, 256, 0, stream>>>(offs, aux);
  k_scatter<<<(TOT_E + 255) / 256, 256, 0, stream>>>(ei, ew, offs, spack, sewt);
  k_main<<<N_ENT / 64, 512, 0, stream>>>(xh, wf, bbf, counts, offs, spack, sewt, out);
}

// Round 11
// 754.867 us; speedup vs baseline: 3.1603x; 1.0452x over previous
//
#include <hip/hip_runtime.h>

// WRGCN: out[t] = sum_r (sum_{e:tgt=t,rel=r} ew_e * X[src_e]) @ W_r + X[t] @ W_self + P @ bias
// Counting-sort edges by key = r*N + tgt. k_main: 512 thr / 64 targets; wave w owns keys
// [n0+8w, n0+8w+8). Double-buffered As (2x32KB) with merged phases: per rel, issue next
// rel's gathers -> MFMA current rel (hides gather latency) -> finish aggregation -> ONE
// barrier. Meta + first edge chunks prefetched at block start. r10-proven layouts.

#define N_ENT 200000
#define D 256
#define R_REL 8
#define E_EDGE 150000
#define TOT_E (R_REL * E_EDGE)        // 1,200,000
#define MKEY (N_ENT * R_REL)          // 1,600,000
#define SCAN_B 1024
#define NBLK_SCAN ((MKEY + SCAN_B - 1) / SCAN_B)   // 1563

typedef __bf16 bf16x8 __attribute__((ext_vector_type(8)));
typedef unsigned short u16x8 __attribute__((ext_vector_type(8)));
typedef float f32x4 __attribute__((ext_vector_type(4)));

__device__ __forceinline__ unsigned short f2bf(float f) {
  unsigned int u = __builtin_bit_cast(unsigned int, f);
  u += 0x7FFFu + ((u >> 16) & 1u);   // RNE (inputs finite)
  return (unsigned short)(u >> 16);
}
__device__ __forceinline__ float bf2f(unsigned short u) {
  return __builtin_bit_cast(float, ((unsigned)u) << 16);
}
__device__ __forceinline__ f32x4 mfma16(u16x8 a, u16x8 b, f32x4 c) {
  return __builtin_amdgcn_mfma_f32_16x16x32_bf16(
      __builtin_bit_cast(bf16x8, a), __builtin_bit_cast(bf16x8, b), c, 0, 0, 0);
}

// ---- X (f32) -> Xh (bf16) ----
__global__ __launch_bounds__(256) void k_cvt_x(const float* __restrict__ x,
                                               unsigned short* __restrict__ xh) {
  int i = blockIdx.x * 256 + threadIdx.x;
  const float4* xv = (const float4*)x;
  float4 a = xv[2 * i], b = xv[2 * i + 1];
  uint4 o;
  o.x = (unsigned)f2bf(a.x) | ((unsigned)f2bf(a.y) << 16);
  o.y = (unsigned)f2bf(a.z) | ((unsigned)f2bf(a.w) << 16);
  o.z = (unsigned)f2bf(b.x) | ((unsigned)f2bf(b.y) << 16);
  o.w = (unsigned)f2bf(b.z) | ((unsigned)f2bf(b.w) << 16);
  ((uint4*)xh)[i] = o;
}

// ---- Weights -> bf16 MFMA B-fragment order. tile 0..7 = W_r, 8 = self ----
__global__ __launch_bounds__(256) void k_cvt_w(const float* __restrict__ relw,
                                               const float* __restrict__ selfw,
                                               unsigned short* __restrict__ wf) {
  int t = blockIdx.x * 256 + threadIdx.x;   // 9*8*16*64 = 73728
  int rel = t >> 13;
  int rem = t & 8191;
  int kb = rem >> 10;
  int nb = (rem >> 6) & 15;
  int lane = rem & 63;
  const float* W = (rel < R_REL) ? (relw + rel * D * D) : selfw;
  int k0 = kb * 32 + (lane >> 4) * 8;
  int n = nb * 16 + (lane & 15);
  unsigned int o[4];
#pragma unroll
  for (int jj = 0; jj < 4; ++jj) {
    unsigned lo = f2bf(W[(k0 + 2 * jj) * D + n]);
    unsigned hi = f2bf(W[(k0 + 2 * jj + 1) * D + n]);
    o[jj] = lo | (hi << 16);
  }
  ((uint4*)wf)[t] = make_uint4(o[0], o[1], o[2], o[3]);
}

// ---- bias -> B-fragment tile for K=8 presence MFMA ----
__global__ __launch_bounds__(256) void k_cvt_bias(const float* __restrict__ bias,
                                                  unsigned short* __restrict__ bb) {
  int t = blockIdx.x * 256 + threadIdx.x;   // 1024
  int nb = t >> 6, lane = t & 63;
  int lk = lane >> 4, n = nb * 16 + (lane & 15);
  unsigned int o[4];
#pragma unroll
  for (int jj = 0; jj < 4; ++jj) {
    unsigned lo = 0, hi = 0;
    if (lk == 0) {
      lo = f2bf(bias[(2 * jj) * D + n]);
      hi = f2bf(bias[(2 * jj + 1) * D + n]);
    }
    o[jj] = lo | (hi << 16);
  }
  ((uint4*)bb)[t] = make_uint4(o[0], o[1], o[2], o[3]);
}

// ---- histogram over key = r*N + tgt ----
__global__ __launch_bounds__(256) void k_hist(const int* __restrict__ ei,
                                              unsigned* __restrict__ counts) {
  int t = blockIdx.x * 256 + threadIdx.x;
  if (t >= TOT_E) return;
  int r = t / E_EDGE, e = t - r * E_EDGE;
  int tgt = ei[(r * 2 + 1) * E_EDGE + e];
  atomicAdd(&counts[r * N_ENT + tgt], 1u);
}

// ---- exclusive scan (3 kernels) ----
__global__ __launch_bounds__(256) void k_scan1(const unsigned* __restrict__ cnt,
                                               unsigned* __restrict__ off,
                                               unsigned* __restrict__ aux) {
  __shared__ unsigned sc[256];
  int tid = threadIdx.x;
  int base = blockIdx.x * SCAN_B + tid * 4;
  unsigned v[4];
#pragma unroll
  for (int j = 0; j < 4; ++j) v[j] = (base + j < MKEY) ? cnt[base + j] : 0u;
  unsigned s = v[0] + v[1] + v[2] + v[3];
  sc[tid] = s;
  __syncthreads();
  for (int o = 1; o < 256; o <<= 1) {
    unsigned t = (tid >= o) ? sc[tid - o] : 0u;
    __syncthreads();
    sc[tid] += t;
    __syncthreads();
  }
  unsigned excl = sc[tid] - s;
  if (tid == 255) aux[blockIdx.x] = sc[255];
#pragma unroll
  for (int j = 0; j < 4; ++j) {
    if (base + j < MKEY) off[base + j] = excl;
    excl += v[j];
  }
}

__global__ __launch_bounds__(256) void k_scan2(unsigned* __restrict__ aux) {
  __shared__ unsigned sc[256];
  int tid = threadIdx.x;
  int base = tid * 7;
  unsigned v[7];
#pragma unroll
  for (int j = 0; j < 7; ++j) v[j] = (base + j < NBLK_SCAN) ? aux[base + j] : 0u;
  unsigned s = 0;
#pragma unroll
  for (int j = 0; j < 7; ++j) s += v[j];
  sc[tid] = s;
  __syncthreads();
  for (int o = 1; o < 256; o <<= 1) {
    unsigned t = (tid >= o) ? sc[tid - o] : 0u;
    __syncthreads();
    sc[tid] += t;
    __syncthreads();
  }
  unsigned excl = sc[tid] - s;
#pragma unroll
  for (int j = 0; j < 7; ++j) {
    if (base + j < NBLK_SCAN) aux[base + j] = excl;
    excl += v[j];
  }
}

__global__ __launch_bounds__(256) void k_scan3(unsigned* __restrict__ off,
                                               const unsigned* __restrict__ aux) {
  unsigned add = aux[blockIdx.x];
  int base = blockIdx.x * SCAN_B + threadIdx.x * 4;
  if (base + 3 < MKEY) {
    uint4* p = (uint4*)(off + base);
    uint4 x = *p;
    x.x += add; x.y += add; x.z += add; x.w += add;
    *p = x;
  } else {
    for (int j = 0; j < 4; ++j)
      if (base + j < MKEY) off[base + j] += add;
  }
}

// ---- scatter (src | (tgt&63)<<18, ew); off becomes segment ENDs ----
__global__ __launch_bounds__(256) void k_scatter(const int* __restrict__ ei,
                                                 const float* __restrict__ ew,
                                                 unsigned* __restrict__ off,
                                                 unsigned* __restrict__ spack,
                                                 float* __restrict__ sewt) {
  int t = blockIdx.x * 256 + threadIdx.x;
  if (t >= TOT_E) return;
  int r = t / E_EDGE, e = t - r * E_EDGE;
  int tgt = ei[(r * 2 + 1) * E_EDGE + e];
  int src = ei[(r * 2) * E_EDGE + e];
  float w = ew[t];
  unsigned pos = atomicAdd(&off[r * N_ENT + tgt], 1u);
  spack[pos] = (unsigned)src | ((unsigned)(tgt & 63) << 18);
  sewt[pos] = w;
}

// ---- aggregation helpers (wave-local, run-length over sorted contiguous range) ----
__device__ __forceinline__ void agg_issue(int g0, int lane, unsigned s0, unsigned e0,
                                          unsigned pkc, float wtc,
                                          const unsigned short* __restrict__ xh,
                                          unsigned char* nxt,
                                          unsigned pk8[8], float wt8[8], ushort4 xv[8]) {
  // zero my 8 rows (flushes overwrite later; same-lane LDS ops are ordered)
#pragma unroll
  for (int k = 0; k < 8; ++k) {
    int g = g0 + k;
    int wb = (g * 512 + lane * 8) ^ ((g & 7) << 4);
    *(uint2*)(nxt + wb) = make_uint2(0u, 0u);
  }
  int total = (int)(e0 - s0);
  int m0 = total < 8 ? total : 8;
#pragma unroll
  for (int u = 0; u < 8; ++u) {
    pk8[u] = (unsigned)__shfl((int)pkc, u);
    wt8[u] = __shfl(wtc, u);
  }
#pragma unroll
  for (int u = 0; u < 8; ++u) {
    unsigned srcu = (u < m0) ? (pk8[u] & 0x3FFFFu) : 0u;   // invalid -> row 0 (L1-hot)
    xv[u] = *(const ushort4*)(xh + (size_t)srcu * 256 + lane * 4);
  }
}

__device__ __forceinline__ void agg_finish(int lane, unsigned s0, unsigned e0,
                                           unsigned pkc, float wtc,
                                           const unsigned* __restrict__ spack,
                                           const float* __restrict__ sewt,
                                           const unsigned short* __restrict__ xh,
                                           unsigned char* nxt,
                                           const unsigned pk8[8], const float wt8[8],
                                           const ushort4 xv[8]) {
  int total = (int)(e0 - s0);
  if (total <= 0) return;
  int gp = -1;
  float a0 = 0.f, a1 = 0.f, a2 = 0.f, a3 = 0.f;
#define AGG_FLUSH() do { \
    unsigned lo_ = (unsigned)f2bf(a0) | ((unsigned)f2bf(a1) << 16); \
    unsigned hi_ = (unsigned)f2bf(a2) | ((unsigned)f2bf(a3) << 16); \
    int wb_ = (gp * 512 + lane * 8) ^ ((gp & 7) << 4); \
    *(uint2*)(nxt + wb_) = make_uint2(lo_, hi_); } while (0)

  int mch = total < 64 ? total : 64;
  int m0 = mch < 8 ? mch : 8;
  // group 0: prefetched in agg_issue
#pragma unroll
  for (int u = 0; u < 8; ++u) {
    if (u < m0) {
      int g = (int)(pk8[u] >> 18);
      if (g != gp) {
        if (gp >= 0) AGG_FLUSH();
        a0 = a1 = a2 = a3 = 0.f;
        gp = g;
      }
      float wt = wt8[u];
      a0 += wt * bf2f(xv[u].x);
      a1 += wt * bf2f(xv[u].y);
      a2 += wt * bf2f(xv[u].z);
      a3 += wt * bf2f(xv[u].w);
    }
  }
  // remaining groups of chunk 0 (rare: >8 edges in an 8-key segment)
  for (int g8 = 8; g8 < mch; g8 += 8) {
    unsigned q8[8];
    float v8[8];
#pragma unroll
    for (int u = 0; u < 8; ++u) {
      q8[u] = (unsigned)__shfl((int)pkc, g8 + u);
      v8[u] = __shfl(wtc, g8 + u);
    }
    ushort4 yv[8];
#pragma unroll
    for (int u = 0; u < 8; ++u) {
      unsigned srcu = (g8 + u < mch) ? (q8[u] & 0x3FFFFu) : 0u;
      yv[u] = *(const ushort4*)(xh + (size_t)srcu * 256 + lane * 4);
    }
#pragma unroll
    for (int u = 0; u < 8; ++u) {
      if (g8 + u < mch) {
        int g = (int)(q8[u] >> 18);
        if (g != gp) {
          if (gp >= 0) AGG_FLUSH();
          a0 = a1 = a2 = a3 = 0.f;
          gp = g;
        }
        float wt = v8[u];
        a0 += wt * bf2f(yv[u].x);
        a1 += wt * bf2f(yv[u].y);
        a2 += wt * bf2f(yv[u].z);
        a3 += wt * bf2f(yv[u].w);
      }
    }
  }
  // remaining chunks (very rare: >64 edges)
  for (unsigned chunk = s0 + 64u; chunk < e0; chunk += 64u) {
    unsigned idx = chunk + (unsigned)lane;
    if (idx >= (unsigned)TOT_E) idx = (unsigned)(TOT_E - 1);
    unsigned pkv = spack[idx];
    float wtv = sewt[idx];
    int rem = (int)(e0 - chunk);
    int m = rem < 64 ? rem : 64;
    for (int g8 = 0; g8 < m; g8 += 8) {
      unsigned q8[8];
      float v8[8];
#pragma unroll
      for (int u = 0; u < 8; ++u) {
        q8[u] = (unsigned)__shfl((int)pkv, g8 + u);
        v8[u] = __shfl(wtv, g8 + u);
      }
      ushort4 yv[8];
#pragma unroll
      for (int u = 0; u < 8; ++u) {
        unsigned srcu = (g8 + u < m) ? (q8[u] & 0x3FFFFu) : 0u;
        yv[u] = *(const ushort4*)(xh + (size_t)srcu * 256 + lane * 4);
      }
#pragma unroll
      for (int u = 0; u < 8; ++u) {
        if (g8 + u < m) {
          int g = (int)(q8[u] >> 18);
          if (g != gp) {
            if (gp >= 0) AGG_FLUSH();
            a0 = a1 = a2 = a3 = 0.f;
            gp = g;
          }
          float wt = v8[u];
          a0 += wt * bf2f(yv[u].x);
          a1 += wt * bf2f(yv[u].y);
          a2 += wt * bf2f(yv[u].z);
          a3 += wt * bf2f(yv[u].w);
        }
      }
    }
  }
  if (gp >= 0) AGG_FLUSH();
#undef AGG_FLUSH
}

// ---- fused main: 512 threads, 64 targets/block, double-buffered As, 1 barrier/rel ----
__global__ __launch_bounds__(512, 2) void k_main(const unsigned short* __restrict__ xh,
                                                 const unsigned short* __restrict__ wf,
                                                 const unsigned short* __restrict__ bbf,
                                                 const unsigned* __restrict__ counts,
                                                 const unsigned* __restrict__ off_end,
                                                 const unsigned* __restrict__ spack,
                                                 const float* __restrict__ sewt,
                                                 float* __restrict__ out) {
  __shared__ __align__(16) unsigned char As[2 * 32768];   // double-buffered 64x256 bf16
  int n0 = blockIdx.x * 64;
  int tid = threadIdx.x;
  int w = tid >> 6, lane = tid & 63;
  int lm = lane & 15, lk = lane >> 4;
  int rbase = (w >> 2) * 32;          // wave's 32-row half for MFMA
  int cbase = (w & 3) * 4;            // wave's 4 nb columns (64 cols)
  int g0 = w * 8;                     // wave's first owned row

  // ---- prefetch 1: all 8 rels' segment bounds (16 independent loads) ----
  unsigned sB[8], eE[8];
#pragma unroll
  for (int r = 0; r < 8; ++r) {
    int kb2 = r * N_ENT + n0 + w * 8;
    sB[r] = kb2 ? off_end[kb2 - 1] : 0u;
    eE[r] = off_end[kb2 + 7];
  }

  f32x4 acc[2][4] = {};

  // ---- self phase (hides meta latency): A-frags direct from global bf16 X ----
  {
    const unsigned short* wfb = wf + 8 * 65536;
#pragma unroll
    for (int kb = 0; kb < 8; ++kb) {
      u16x8 a[2], b[4];
#pragma unroll
      for (int mi = 0; mi < 2; ++mi)
        a[mi] = *(const u16x8*)(xh + (size_t)(n0 + rbase + mi * 16 + lm) * 256 + kb * 32 + lk * 8);
#pragma unroll
      for (int ni = 0; ni < 4; ++ni)
        b[ni] = *(const u16x8*)(wfb + ((kb * 16 + cbase + ni) * 64 + lane) * 8);
#pragma unroll
      for (int mi = 0; mi < 2; ++mi)
#pragma unroll
        for (int ni = 0; ni < 4; ++ni)
          acc[mi][ni] = mfma16(a[mi], b[ni], acc[mi][ni]);
    }
  }

  // ---- prefetch 2: first 64-edge chunk per rel (16 independent loads) ----
  unsigned pk0[8];
  float wt0[8];
#pragma unroll
  for (int r = 0; r < 8; ++r) {
    unsigned idx = sB[r] + (unsigned)lane;
    if (idx >= (unsigned)TOT_E) idx = (unsigned)(TOT_E - 1);
    pk0[r] = spack[idx];
    wt0[r] = sewt[idx];
  }

  // ---- prologue: aggregate rel 0 into As[0] ----
  {
    unsigned pk8[8];
    float wt8[8];
    ushort4 xv[8];
    agg_issue(g0, lane, sB[0], eE[0], pk0[0], wt0[0], xh, As, pk8, wt8, xv);
    agg_finish(lane, sB[0], eE[0], pk0[0], wt0[0], spack, sewt, xh, As, pk8, wt8, xv);
  }
  __syncthreads();

  // ---- pipelined rel loop: one barrier per rel ----
#pragma unroll
  for (int r = 0; r < 8; ++r) {
    unsigned char* cur = As + (r & 1) * 32768;
    unsigned char* nxt = As + ((r + 1) & 1) * 32768;
    unsigned pk8[8];
    float wt8[8];
    ushort4 xv[8];
    if (r < 7)
      agg_issue(g0, lane, sB[r + 1], eE[r + 1], pk0[r + 1], wt0[r + 1], xh, nxt, pk8, wt8, xv);

    // MFMA(r) from cur — hides the just-issued gathers
    const unsigned short* wfb = wf + r * 65536;
#pragma unroll
    for (int kb = 0; kb < 8; ++kb) {
      u16x8 a[2], b[4];
#pragma unroll
      for (int mi = 0; mi < 2; ++mi) {
        int row = rbase + mi * 16 + lm;
        int byt = (row * 512 + kb * 64 + lk * 16) ^ ((row & 7) << 4);
        a[mi] = *(const u16x8*)(cur + byt);
      }
#pragma unroll
      for (int ni = 0; ni < 4; ++ni)
        b[ni] = *(const u16x8*)(wfb + ((kb * 16 + cbase + ni) * 64 + lane) * 8);
#pragma unroll
      for (int mi = 0; mi < 2; ++mi)
#pragma unroll
        for (int ni = 0; ni < 4; ++ni)
          acc[mi][ni] = mfma16(a[mi], b[ni], acc[mi][ni]);
    }

    if (r < 7)
      agg_finish(lane, sB[r + 1], eE[r + 1], pk0[r + 1], wt0[r + 1], spack, sewt, xh, nxt,
                 pk8, wt8, xv);
    __syncthreads();
  }

  // ---- bias via presence MFMA: P[64x8] @ bias[8x256] ----
  {
    u16x8 bb[4];
#pragma unroll
    for (int ni = 0; ni < 4; ++ni)
      bb[ni] = *(const u16x8*)(bbf + ((cbase + ni) * 64 + lane) * 8);
#pragma unroll
    for (int mi = 0; mi < 2; ++mi) {
      u16x8 pa = {};
      if (lk == 0) {
        int n = n0 + rbase + mi * 16 + lm;
#pragma unroll
        for (int r = 0; r < 8; ++r)
          pa[r] = counts[r * N_ENT + n] ? 0x3F80 : 0;
      }
#pragma unroll
      for (int ni = 0; ni < 4; ++ni)
        acc[mi][ni] = mfma16(pa, bb[ni], acc[mi][ni]);
    }
  }

  // ---- epilogue ----
#pragma unroll
  for (int mi = 0; mi < 2; ++mi)
#pragma unroll
    for (int ni = 0; ni < 4; ++ni) {
      int col = (w & 3) * 64 + ni * 16 + lm;
#pragma unroll
      for (int j = 0; j < 4; ++j) {
        int row = n0 + rbase + mi * 16 + lk * 4 + j;
        out[row * 256 + col] = acc[mi][ni][j];
      }
    }
}

extern "C" void kernel_launch(void* const* d_in, const int* in_sizes, int n_in,
                              void* d_out, int out_size, void* d_ws, size_t ws_size,
                              hipStream_t stream) {
  const float* x = (const float*)d_in[0];
  const float* relw = (const float*)d_in[1];
  const float* selfw = (const float*)d_in[2];
  const float* bias = (const float*)d_in[3];
  const int* ei = (const int*)d_in[4];
  const float* ew = (const float*)d_in[5];
  float* out = (float*)d_out;

  char* ws = (char*)d_ws;
  unsigned short* xh = (unsigned short*)ws;                          // 102,400,000
  unsigned short* wf = (unsigned short*)(ws + 102400000);            //   1,179,648
  unsigned short* bbf = (unsigned short*)(ws + 103579648);           //      16,384
  unsigned* counts = (unsigned*)(ws + 103596032);                    //   6,400,000
  unsigned* offs = (unsigned*)(ws + 109996032);                      //   6,400,000
  unsigned* aux = (unsigned*)(ws + 116396032);                       //       8,192
  unsigned* spack = (unsigned*)(ws + 116404224);                     //   4,800,000
  float* sewt = (float*)(ws + 121204224);                            //   4,800,000

  hipMemsetAsync(counts, 0, (size_t)MKEY * 4, stream);
  k_cvt_x<<<(N_ENT * D) / 2048, 256, 0, stream>>>(x, xh);
  k_cvt_w<<<288, 256, 0, stream>>>(relw, selfw, wf);
  k_cvt_bias<<<4, 256, 0, stream>>>(bias, bbf);
  k_hist<<<(TOT_E + 255) / 256, 256, 0, stream>>>(ei, counts);
  k_scan1<<<NBLK_SCAN, 256, 0, stream>>>(counts, offs, aux);
  k_scan2<<<1, 256, 0, stream>>>(aux);
  k_scan3<<<NBLK_SCAN, 256, 0, stream>>>(offs, aux);
  k_scatter<<<(TOT_E + 255) / 256, 256, 0, stream>>>(ei, ew, offs, spack, sewt);
  k_main<<<N_ENT / 64, 512, 0, stream>>>(xh, wf, bbf, counts, offs, spack, sewt, out);
}